// Round 1
// baseline (1496.918 us; speedup 1.0000x reference)
//
#include <hip/hip_runtime.h>

#define N_NODES 100000
#define N_EDGES 1600000
#define N_GRAPHS 1000
#define H 128
#define DEPTH 4

// ---------------- CSR build (by dst) ----------------
__global__ void k_hist(const int* __restrict__ dst, int* __restrict__ cnt) {
  int e = blockIdx.x * 256 + threadIdx.x;
  if (e < N_EDGES) atomicAdd(&cnt[dst[e]], 1);
}

// 98 blocks x 256 threads x 4 elems = 100352 slots >= 100000
__global__ void k_scan1(const int* __restrict__ cnt, int* __restrict__ exc, int* __restrict__ aux) {
  __shared__ int sh[256];
  int t = threadIdx.x, b = blockIdx.x;
  int base = b * 1024 + t * 4;
  int v[4], tsum = 0;
#pragma unroll
  for (int j = 0; j < 4; ++j) {
    int idx = base + j;
    v[j] = (idx < N_NODES) ? cnt[idx] : 0;
    tsum += v[j];
  }
  sh[t] = tsum;
  __syncthreads();
  for (int off = 1; off < 256; off <<= 1) {
    int x = (t >= off) ? sh[t - off] : 0;
    __syncthreads();
    sh[t] += x;
    __syncthreads();
  }
  int run = sh[t] - tsum;  // exclusive prefix within block
  if (t == 255) aux[b] = sh[255];
#pragma unroll
  for (int j = 0; j < 4; ++j) {
    int idx = base + j;
    if (idx < N_NODES) exc[idx] = run;
    run += v[j];
  }
}

__global__ void k_scan2(int* aux, int nb) {
  __shared__ int sh[128];
  int t = threadIdx.x;
  int v = (t < nb) ? aux[t] : 0;
  sh[t] = v;
  __syncthreads();
  for (int off = 1; off < 128; off <<= 1) {
    int x = (t >= off) ? sh[t - off] : 0;
    __syncthreads();
    sh[t] += x;
    __syncthreads();
  }
  if (t < nb) aux[t] = sh[t] - v;
}

__global__ void k_scan3(int* __restrict__ offs, const int* __restrict__ aux) {
  int b = blockIdx.x;
  int base = b * 1024 + threadIdx.x * 4;
  int a = aux[b];
#pragma unroll
  for (int j = 0; j < 4; ++j) {
    int idx = base + j;
    if (idx < N_NODES) offs[idx] += a;
  }
  if (b == 0 && threadIdx.x == 0) offs[N_NODES] = N_EDGES;
}

__global__ void k_scatter(const int* __restrict__ src, const int* __restrict__ dst,
                          int* __restrict__ cursor, int* __restrict__ csr) {
  int e = blockIdx.x * 256 + threadIdx.x;
  if (e < N_EDGES) {
    int d = dst[e];
    int pos = atomicAdd(&cursor[d], 1);
    csr[pos] = src[e];
  }
}

// ---------------- Linear 0: h0 = relu(x @ W0 + b0) ----------------
// 32 nodes/block, 256 threads; W staged per 32-k chunk (16 KB), input tile
// transposed in LDS (stride 36 -> 16B-aligned float4 rows, bank-spread).
__global__ __launch_bounds__(256) void k_lin(const float* __restrict__ in, const float* __restrict__ Wg,
                                             const float* __restrict__ bg, float* __restrict__ outp) {
  __shared__ float Wc[32 * 128];
  __shared__ float xt[128 * 36];
  int tid = threadIdx.x;
  int n0 = blockIdx.x * 32;
  int cg = tid & 31, ng = tid >> 5;  // cols 4*cg.., nodes 4*ng..
  for (int idx = tid; idx < 32 * 128; idx += 256) {
    int node = idx >> 7, k = idx & 127;
    xt[k * 36 + node] = in[(size_t)(n0 + node) * H + k];
  }
  float4 bv = *(const float4*)&bg[cg * 4];
  float acc[4][4];
#pragma unroll
  for (int i = 0; i < 4; ++i) { acc[i][0] = bv.x; acc[i][1] = bv.y; acc[i][2] = bv.z; acc[i][3] = bv.w; }
  __syncthreads();
  for (int ch = 0; ch < 4; ++ch) {
#pragma unroll
    for (int idx = tid * 4; idx < 4096; idx += 1024)
      *(float4*)&Wc[idx] = *(const float4*)&Wg[ch * 4096 + idx];
    __syncthreads();
#pragma unroll
    for (int kl = 0; kl < 32; ++kl) {
      float4 w = *(float4*)&Wc[kl * 128 + cg * 4];
      float4 xv = *(float4*)&xt[(ch * 32 + kl) * 36 + ng * 4];
      float xa[4] = {xv.x, xv.y, xv.z, xv.w};
      float wa[4] = {w.x, w.y, w.z, w.w};
#pragma unroll
      for (int i = 0; i < 4; ++i)
#pragma unroll
        for (int j = 0; j < 4; ++j) acc[i][j] += xa[i] * wa[j];
    }
    __syncthreads();
  }
#pragma unroll
  for (int i = 0; i < 4; ++i) {
    float4 r;
    r.x = fmaxf(acc[i][0], 0.f);
    r.y = fmaxf(acc[i][1], 0.f);
    r.z = fmaxf(acc[i][2], 0.f);
    r.w = fmaxf(acc[i][3], 0.f);
    *(float4*)&outp[(size_t)(n0 + ng * 4 + i) * H + cg * 4] = r;
  }
}

// ---------------- Aggregation: zin[n] = h[n] + sum_{e in CSR(n)} h[src[e]] ----------------
// one wave per node, float2 per lane -> 512B coalesced row reads
__global__ __launch_bounds__(256) void k_agg(const float* __restrict__ hin, const int* __restrict__ offs,
                                             const int* __restrict__ csr, float* __restrict__ zin) {
  int node = blockIdx.x * 4 + (threadIdx.x >> 6);
  int lane = threadIdx.x & 63;
  if (node >= N_NODES) return;
  float2 acc = ((const float2*)(hin + (size_t)node * H))[lane];
  int beg = offs[node], end = offs[node + 1];
  for (int e = beg; e < end; e += 64) {
    int cnt = min(64, end - e);
    int idx = (lane < cnt) ? csr[e + lane] : 0;
    for (int j = 0; j < cnt; ++j) {
      int s = __shfl(idx, j);
      float2 v = ((const float2*)(hin + (size_t)s * H))[lane];
      acc.x += v.x;
      acc.y += v.y;
    }
  }
  ((float2*)(zin + (size_t)node * H))[lane] = acc;
}

// ---------------- Fused MLP: h = relu( relu(zin@W1+b1)@W2 + b2 + h0 ) ----------------
__global__ __launch_bounds__(256) void k_mlp(const float* __restrict__ zin,
                                             const float* __restrict__ W1g, const float* __restrict__ b1g,
                                             const float* __restrict__ W2g, const float* __restrict__ b2g,
                                             const float* __restrict__ h0, float* __restrict__ h) {
  __shared__ float Wc[32 * 128];
  __shared__ float xt[128 * 36];
  __shared__ float z1t[128 * 36];
  int tid = threadIdx.x;
  int n0 = blockIdx.x * 32;
  int cg = tid & 31, ng = tid >> 5;
  for (int idx = tid; idx < 32 * 128; idx += 256) {
    int node = idx >> 7, k = idx & 127;
    xt[k * 36 + node] = zin[(size_t)(n0 + node) * H + k];
  }
  float acc[4][4];
  {
    float4 bv = *(const float4*)&b1g[cg * 4];
#pragma unroll
    for (int i = 0; i < 4; ++i) { acc[i][0] = bv.x; acc[i][1] = bv.y; acc[i][2] = bv.z; acc[i][3] = bv.w; }
  }
  __syncthreads();
  // phase A: z1 = relu(zin @ W1 + b1)
  for (int ch = 0; ch < 4; ++ch) {
#pragma unroll
    for (int idx = tid * 4; idx < 4096; idx += 1024)
      *(float4*)&Wc[idx] = *(const float4*)&W1g[ch * 4096 + idx];
    __syncthreads();
#pragma unroll
    for (int kl = 0; kl < 32; ++kl) {
      float4 w = *(float4*)&Wc[kl * 128 + cg * 4];
      float4 xv = *(float4*)&xt[(ch * 32 + kl) * 36 + ng * 4];
      float xa[4] = {xv.x, xv.y, xv.z, xv.w};
      float wa[4] = {w.x, w.y, w.z, w.w};
#pragma unroll
      for (int i = 0; i < 4; ++i)
#pragma unroll
        for (int j = 0; j < 4; ++j) acc[i][j] += xa[i] * wa[j];
    }
    __syncthreads();
  }
  // store z1 transposed (k-major) for phase B
#pragma unroll
  for (int j = 0; j < 4; ++j) {
    float4 r;
    r.x = fmaxf(acc[0][j], 0.f);
    r.y = fmaxf(acc[1][j], 0.f);
    r.z = fmaxf(acc[2][j], 0.f);
    r.w = fmaxf(acc[3][j], 0.f);
    *(float4*)&z1t[(cg * 4 + j) * 36 + ng * 4] = r;
  }
  float acc2[4][4];
  {
    float4 bv = *(const float4*)&b2g[cg * 4];
#pragma unroll
    for (int i = 0; i < 4; ++i) { acc2[i][0] = bv.x; acc2[i][1] = bv.y; acc2[i][2] = bv.z; acc2[i][3] = bv.w; }
  }
  // phase B: z = z1 @ W2 + b2 ; h = relu(z + h0)
  for (int ch = 0; ch < 4; ++ch) {
#pragma unroll
    for (int idx = tid * 4; idx < 4096; idx += 1024)
      *(float4*)&Wc[idx] = *(const float4*)&W2g[ch * 4096 + idx];
    __syncthreads();
#pragma unroll
    for (int kl = 0; kl < 32; ++kl) {
      float4 w = *(float4*)&Wc[kl * 128 + cg * 4];
      float4 zv = *(float4*)&z1t[(ch * 32 + kl) * 36 + ng * 4];
      float za[4] = {zv.x, zv.y, zv.z, zv.w};
      float wa[4] = {w.x, w.y, w.z, w.w};
#pragma unroll
      for (int i = 0; i < 4; ++i)
#pragma unroll
        for (int j = 0; j < 4; ++j) acc2[i][j] += za[i] * wa[j];
    }
    __syncthreads();
  }
#pragma unroll
  for (int i = 0; i < 4; ++i) {
    size_t row = (size_t)(n0 + ng * 4 + i) * H + cg * 4;
    float4 hv = *(const float4*)&h0[row];
    float4 r;
    r.x = fmaxf(acc2[i][0] + hv.x, 0.f);
    r.y = fmaxf(acc2[i][1] + hv.y, 0.f);
    r.z = fmaxf(acc2[i][2] + hv.z, 0.f);
    r.w = fmaxf(acc2[i][3] + hv.w, 0.f);
    *(float4*)&h[row] = r;
  }
}

// ---------------- Pooling ----------------
__global__ void k_starts(const int* __restrict__ batch, int* __restrict__ starts) {
  int n = blockIdx.x * 256 + threadIdx.x;
  if (n >= N_NODES) return;
  int b = batch[n];
  if (n == 0) {
    for (int g = 0; g <= b; ++g) starts[g] = 0;
  } else {
    int bp = batch[n - 1];
    for (int g = bp + 1; g <= b; ++g) starts[g] = n;
  }
  if (n == N_NODES - 1) {
    for (int g = b + 1; g <= N_GRAPHS; ++g) starts[g] = N_NODES;
  }
}

__global__ __launch_bounds__(128) void k_pool(const float* __restrict__ h, const int* __restrict__ starts,
                                              const float* __restrict__ Wf, const float* __restrict__ bf,
                                              float* __restrict__ out) {
  __shared__ float r[2];
  int g = blockIdx.x, c = threadIdx.x;
  int beg = starts[g], end = starts[g + 1];
  float s = 0.f;
  for (int n = beg; n < end; ++n) s += h[(size_t)n * H + c];
  float v = s * Wf[c];
#pragma unroll
  for (int off = 32; off > 0; off >>= 1) v += __shfl_down(v, off);
  if ((c & 63) == 0) r[c >> 6] = v;
  __syncthreads();
  if (c == 0) out[g] = r[0] + r[1] + bf[0];
}

extern "C" void kernel_launch(void* const* d_in, const int* in_sizes, int n_in,
                              void* d_out, int out_size, void* d_ws, size_t ws_size,
                              hipStream_t stream) {
  const float* x = (const float*)d_in[0];
  const int* ei = (const int*)d_in[1];
  const int* srcv = ei;             // edge_index[0]
  const int* dstv = ei + N_EDGES;   // edge_index[1]
  const int* batch = (const int*)d_in[3];
  const float* W0 = (const float*)d_in[4];
  const float* b0 = (const float*)d_in[5];
  const float* W1 = (const float*)d_in[6];
  const float* b1 = (const float*)d_in[7];
  const float* W2 = (const float*)d_in[8];
  const float* b2 = (const float*)d_in[9];
  const float* Wf = (const float*)d_in[10];
  const float* bf = (const float*)d_in[11];
  float* out = (float*)d_out;

  char* ws = (char*)d_ws;
  size_t o = 0;
  auto alloc = [&](size_t bytes) {
    size_t r = o;
    o = (o + bytes + 255) & ~(size_t)255;
    return r;
  };
  int* offs = (int*)(ws + alloc((N_NODES + 1) * sizeof(int)));
  int* cursor = (int*)(ws + alloc((size_t)N_NODES * sizeof(int)));
  int* csr = (int*)(ws + alloc((size_t)N_EDGES * sizeof(int)));
  int* aux = (int*)(ws + alloc(128 * sizeof(int)));
  int* starts = (int*)(ws + alloc((N_GRAPHS + 1) * sizeof(int)));
  float* h0 = (float*)(ws + alloc((size_t)N_NODES * H * sizeof(float)));
  float* h = (float*)(ws + alloc((size_t)N_NODES * H * sizeof(float)));
  float* zin = (float*)(ws + alloc((size_t)N_NODES * H * sizeof(float)));

  hipMemsetAsync(cursor, 0, (size_t)N_NODES * sizeof(int), stream);
  k_hist<<<(N_EDGES + 255) / 256, 256, 0, stream>>>(dstv, cursor);
  k_scan1<<<98, 256, 0, stream>>>(cursor, offs, aux);
  k_scan2<<<1, 128, 0, stream>>>(aux, 98);
  k_scan3<<<98, 256, 0, stream>>>(offs, aux);
  hipMemcpyAsync(cursor, offs, (size_t)N_NODES * sizeof(int), hipMemcpyDeviceToDevice, stream);
  k_scatter<<<(N_EDGES + 255) / 256, 256, 0, stream>>>(srcv, dstv, cursor, csr);
  k_starts<<<(N_NODES + 255) / 256, 256, 0, stream>>>(batch, starts);

  k_lin<<<N_NODES / 32, 256, 0, stream>>>(x, W0, b0, h0);
  for (int i = 0; i < DEPTH; ++i) {
    const float* hin = (i == 0) ? h0 : h;
    k_agg<<<N_NODES / 4, 256, 0, stream>>>(hin, offs, csr, zin);
    k_mlp<<<N_NODES / 32, 256, 0, stream>>>(zin, W1 + (size_t)i * H * H, b1 + (size_t)i * H,
                                            W2 + (size_t)i * H * H, b2 + (size_t)i * H, h0, h);
  }
  k_pool<<<N_GRAPHS, 128, 0, stream>>>(h, starts, Wf, bf, out);
}

// Round 2
// 1007.729 us; speedup vs baseline: 1.4854x; 1.4854x over previous
//
#include <hip/hip_runtime.h>

#define N_NODES 100000
#define N_EDGES 1600000
#define N_GRAPHS 1000
#define H 128
#define DEPTH 4

typedef __attribute__((ext_vector_type(8))) short bf16x8;
typedef __attribute__((ext_vector_type(4))) float f32x4;

__device__ __forceinline__ unsigned short f2bf(float f) {
  unsigned int u = __float_as_uint(f);
  u += 0x7FFF + ((u >> 16) & 1);
  return (unsigned short)(u >> 16);
}
__device__ __forceinline__ float bflo(unsigned int v) { return __uint_as_float(v << 16); }
__device__ __forceinline__ float bfhi(unsigned int v) { return __uint_as_float(v & 0xFFFF0000u); }

// ---------------- CSR build (by dst) ----------------
__global__ void k_hist(const int* __restrict__ dst, int* __restrict__ cnt) {
  int e = blockIdx.x * 256 + threadIdx.x;
  if (e < N_EDGES) atomicAdd(&cnt[dst[e]], 1);
}

__global__ void k_scan1(const int* __restrict__ cnt, int* __restrict__ exc, int* __restrict__ aux) {
  __shared__ int sh[256];
  int t = threadIdx.x, b = blockIdx.x;
  int base = b * 1024 + t * 4;
  int v[4], tsum = 0;
#pragma unroll
  for (int j = 0; j < 4; ++j) {
    int idx = base + j;
    v[j] = (idx < N_NODES) ? cnt[idx] : 0;
    tsum += v[j];
  }
  sh[t] = tsum;
  __syncthreads();
  for (int off = 1; off < 256; off <<= 1) {
    int x = (t >= off) ? sh[t - off] : 0;
    __syncthreads();
    sh[t] += x;
    __syncthreads();
  }
  int run = sh[t] - tsum;
  if (t == 255) aux[b] = sh[255];
#pragma unroll
  for (int j = 0; j < 4; ++j) {
    int idx = base + j;
    if (idx < N_NODES) exc[idx] = run;
    run += v[j];
  }
}

__global__ void k_scan2(int* aux, int nb) {
  __shared__ int sh[128];
  int t = threadIdx.x;
  int v = (t < nb) ? aux[t] : 0;
  sh[t] = v;
  __syncthreads();
  for (int off = 1; off < 128; off <<= 1) {
    int x = (t >= off) ? sh[t - off] : 0;
    __syncthreads();
    sh[t] += x;
    __syncthreads();
  }
  if (t < nb) aux[t] = sh[t] - v;
}

__global__ void k_scan3(int* __restrict__ offs, const int* __restrict__ aux) {
  int b = blockIdx.x;
  int base = b * 1024 + threadIdx.x * 4;
  int a = aux[b];
#pragma unroll
  for (int j = 0; j < 4; ++j) {
    int idx = base + j;
    if (idx < N_NODES) offs[idx] += a;
  }
  if (b == 0 && threadIdx.x == 0) offs[N_NODES] = N_EDGES;
}

__global__ void k_scatter(const int* __restrict__ src, const int* __restrict__ dst,
                          int* __restrict__ cursor, int* __restrict__ csr) {
  int e = blockIdx.x * 256 + threadIdx.x;
  if (e < N_EDGES) {
    int d = dst[e];
    int pos = atomicAdd(&cursor[d], 1);
    csr[pos] = src[e];
  }
}

// ---------------- stage W (fp32 KxN) transposed into LDS Wt[n][k] bf16, pad 136 ----------------
__device__ __forceinline__ void stage_w(const float* __restrict__ Wg, unsigned short* Wt, int tid) {
  for (int idx = tid; idx < 2048; idx += 256) {
    int ng4 = idx & 31, kp = idx >> 5;  // n = 4*ng4 .. +3 ; k = 2*kp, 2*kp+1
    float4 r0 = *(const float4*)&Wg[(2 * kp) * H + 4 * ng4];
    float4 r1 = *(const float4*)&Wg[(2 * kp + 1) * H + 4 * ng4];
    unsigned int p0 = (unsigned int)f2bf(r0.x) | ((unsigned int)f2bf(r1.x) << 16);
    unsigned int p1 = (unsigned int)f2bf(r0.y) | ((unsigned int)f2bf(r1.y) << 16);
    unsigned int p2 = (unsigned int)f2bf(r0.z) | ((unsigned int)f2bf(r1.z) << 16);
    unsigned int p3 = (unsigned int)f2bf(r0.w) | ((unsigned int)f2bf(r1.w) << 16);
    *(unsigned int*)&Wt[(4 * ng4 + 0) * 136 + 2 * kp] = p0;
    *(unsigned int*)&Wt[(4 * ng4 + 1) * 136 + 2 * kp] = p1;
    *(unsigned int*)&Wt[(4 * ng4 + 2) * 136 + 2 * kp] = p2;
    *(unsigned int*)&Wt[(4 * ng4 + 3) * 136 + 2 * kp] = p3;
  }
}

// ---------------- Linear 0 (MFMA): h0 = relu(x @ W0 + b0), x fp32, h0 bf16 ----------------
__global__ __launch_bounds__(256) void k_lin(const float* __restrict__ in, const float* __restrict__ Wg,
                                             const float* __restrict__ bg, unsigned short* __restrict__ outp) {
  __shared__ unsigned short Wt[128 * 136];
  __shared__ unsigned short zs[64 * 136];
  int tid = threadIdx.x;
  int lane = tid & 63, w = tid >> 6;
  int q = lane >> 4, l16 = lane & 15;
  int n0 = blockIdx.x * 64;

  stage_w(Wg, Wt, tid);

  int row = n0 + w * 16 + l16;
  int rr = (row < N_NODES) ? row : 0;
  bf16x8 afrag[4];
#pragma unroll
  for (int ks = 0; ks < 4; ++ks) {
    const float* p = &in[(size_t)rr * H + ks * 32 + q * 8];
    float4 f0 = *(const float4*)p;
    float4 f1 = *(const float4*)(p + 4);
    bf16x8 a;
    a[0] = (short)f2bf(f0.x); a[1] = (short)f2bf(f0.y); a[2] = (short)f2bf(f0.z); a[3] = (short)f2bf(f0.w);
    a[4] = (short)f2bf(f1.x); a[5] = (short)f2bf(f1.y); a[6] = (short)f2bf(f1.z); a[7] = (short)f2bf(f1.w);
    afrag[ks] = a;
  }
  f32x4 acc[8];
#pragma unroll
  for (int ct = 0; ct < 8; ++ct) acc[ct] = (f32x4){0.f, 0.f, 0.f, 0.f};
  __syncthreads();
#pragma unroll
  for (int ct = 0; ct < 8; ++ct)
#pragma unroll
    for (int ks = 0; ks < 4; ++ks) {
      bf16x8 b = *(bf16x8*)&Wt[(ct * 16 + l16) * 136 + ks * 32 + q * 8];
      acc[ct] = __builtin_amdgcn_mfma_f32_16x16x32_bf16(afrag[ks], b, acc[ct], 0, 0, 0);
    }
#pragma unroll
  for (int ct = 0; ct < 8; ++ct) {
    float bb = bg[ct * 16 + l16];
#pragma unroll
    for (int r = 0; r < 4; ++r) {
      float v = fmaxf(acc[ct][r] + bb, 0.f);
      zs[(w * 16 + q * 4 + r) * 136 + ct * 16 + l16] = f2bf(v);
    }
  }
  __syncthreads();
  int node = tid >> 2, cb = (tid & 3) * 32;
  if (n0 + node < N_NODES) {
#pragma unroll
    for (int i = 0; i < 4; ++i) {
      uint4 v = *(uint4*)&zs[node * 136 + cb + i * 8];
      *(uint4*)&outp[(size_t)(n0 + node) * H + cb + i * 8] = v;
    }
  }
}

// ---------------- Aggregation: zin[n] = h[n] + sum_{CSR(n)} h[src], bf16 in/out, fp32 accum ----------------
__global__ __launch_bounds__(256) void k_agg(const unsigned short* __restrict__ hin, const int* __restrict__ offs,
                                             const int* __restrict__ csr, unsigned short* __restrict__ zin) {
  int node = blockIdx.x * 4 + (threadIdx.x >> 6);
  int lane = threadIdx.x & 63;
  if (node >= N_NODES) return;
  const unsigned int* hu = (const unsigned int*)hin;
  unsigned int self = hu[(size_t)node * 64 + lane];
  float sx = bflo(self), sy = bfhi(self);
  int beg = offs[node], end = offs[node + 1];
  for (int e = beg; e < end; e += 64) {
    int cnt = min(64, end - e);
    int idx = (lane < cnt) ? csr[e + lane] : 0;
    for (int j = 0; j < cnt; ++j) {
      int s = __shfl(idx, j);
      unsigned int v = hu[(size_t)s * 64 + lane];
      sx += bflo(v);
      sy += bfhi(v);
    }
  }
  unsigned int o = (unsigned int)f2bf(sx) | ((unsigned int)f2bf(sy) << 16);
  ((unsigned int*)zin)[(size_t)node * 64 + lane] = o;
}

// ---------------- Fused MLP (MFMA): h = relu( relu(zin@W1+b1)@W2 + b2 + h0 ), all bf16 storage ----------------
__global__ __launch_bounds__(256) void k_mlp(const unsigned short* __restrict__ zin,
                                             const float* __restrict__ W1g, const float* __restrict__ b1g,
                                             const float* __restrict__ W2g, const float* __restrict__ b2g,
                                             const unsigned short* __restrict__ h0, unsigned short* __restrict__ h) {
  __shared__ unsigned short Wt[128 * 136];
  __shared__ unsigned short zs[64 * 136];
  int tid = threadIdx.x;
  int lane = tid & 63, w = tid >> 6;
  int q = lane >> 4, l16 = lane & 15;
  int n0 = blockIdx.x * 64;

  stage_w(W1g, Wt, tid);

  int row = n0 + w * 16 + l16;
  int rr = (row < N_NODES) ? row : 0;
  bf16x8 afrag[4];
#pragma unroll
  for (int ks = 0; ks < 4; ++ks)
    afrag[ks] = *(bf16x8*)&zin[(size_t)rr * H + ks * 32 + q * 8];

  f32x4 acc[8];
#pragma unroll
  for (int ct = 0; ct < 8; ++ct) acc[ct] = (f32x4){0.f, 0.f, 0.f, 0.f};
  __syncthreads();
  // phase A: z1 = relu(zin @ W1 + b1)
#pragma unroll
  for (int ct = 0; ct < 8; ++ct)
#pragma unroll
    for (int ks = 0; ks < 4; ++ks) {
      bf16x8 b = *(bf16x8*)&Wt[(ct * 16 + l16) * 136 + ks * 32 + q * 8];
      acc[ct] = __builtin_amdgcn_mfma_f32_16x16x32_bf16(afrag[ks], b, acc[ct], 0, 0, 0);
    }
  __syncthreads();  // all waves done reading W1
  stage_w(W2g, Wt, tid);
#pragma unroll
  for (int ct = 0; ct < 8; ++ct) {
    float bb = b1g[ct * 16 + l16];
#pragma unroll
    for (int r = 0; r < 4; ++r) {
      float v = fmaxf(acc[ct][r] + bb, 0.f);
      zs[(w * 16 + q * 4 + r) * 136 + ct * 16 + l16] = f2bf(v);
    }
  }
  __syncthreads();  // W2 staged (zs is same-wave anyway)
  // phase B: z = z1 @ W2
  bf16x8 a2[4];
#pragma unroll
  for (int ks = 0; ks < 4; ++ks)
    a2[ks] = *(bf16x8*)&zs[(w * 16 + l16) * 136 + ks * 32 + q * 8];
  f32x4 acc2[8];
#pragma unroll
  for (int ct = 0; ct < 8; ++ct) acc2[ct] = (f32x4){0.f, 0.f, 0.f, 0.f};
#pragma unroll
  for (int ct = 0; ct < 8; ++ct)
#pragma unroll
    for (int ks = 0; ks < 4; ++ks) {
      bf16x8 b = *(bf16x8*)&Wt[(ct * 16 + l16) * 136 + ks * 32 + q * 8];
      acc2[ct] = __builtin_amdgcn_mfma_f32_16x16x32_bf16(a2[ks], b, acc2[ct], 0, 0, 0);
    }
  // write z (pre-residual) back to zs as bf16
#pragma unroll
  for (int ct = 0; ct < 8; ++ct) {
    float bb = b2g[ct * 16 + l16];
#pragma unroll
    for (int r = 0; r < 4; ++r) {
      float v = acc2[ct][r] + bb;
      zs[(w * 16 + q * 4 + r) * 136 + ct * 16 + l16] = f2bf(v);
    }
  }
  __syncthreads();
  // epilogue: h = relu(z + h0), coalesced
  int node = tid >> 2, cb = (tid & 3) * 32;
  if (n0 + node < N_NODES) {
    size_t base = (size_t)(n0 + node) * H + cb;
#pragma unroll
    for (int i = 0; i < 4; ++i) {
      uint4 zv = *(uint4*)&zs[node * 136 + cb + i * 8];
      uint4 hv = *(const uint4*)&h0[base + i * 8];
      unsigned int zr[4] = {zv.x, zv.y, zv.z, zv.w};
      unsigned int hr[4] = {hv.x, hv.y, hv.z, hv.w};
      uint4 o;
      unsigned int orr[4];
#pragma unroll
      for (int j = 0; j < 4; ++j) {
        float a = fmaxf(bflo(zr[j]) + bflo(hr[j]), 0.f);
        float b = fmaxf(bfhi(zr[j]) + bfhi(hr[j]), 0.f);
        orr[j] = (unsigned int)f2bf(a) | ((unsigned int)f2bf(b) << 16);
      }
      o.x = orr[0]; o.y = orr[1]; o.z = orr[2]; o.w = orr[3];
      *(uint4*)&h[base + i * 8] = o;
    }
  }
}

// ---------------- Pooling ----------------
__global__ void k_starts(const int* __restrict__ batch, int* __restrict__ starts) {
  int n = blockIdx.x * 256 + threadIdx.x;
  if (n >= N_NODES) return;
  int b = batch[n];
  if (n == 0) {
    for (int g = 0; g <= b; ++g) starts[g] = 0;
  } else {
    int bp = batch[n - 1];
    for (int g = bp + 1; g <= b; ++g) starts[g] = n;
  }
  if (n == N_NODES - 1) {
    for (int g = b + 1; g <= N_GRAPHS; ++g) starts[g] = N_NODES;
  }
}

__global__ __launch_bounds__(64) void k_pool(const unsigned short* __restrict__ h, const int* __restrict__ starts,
                                             const float* __restrict__ Wf, const float* __restrict__ bf_,
                                             float* __restrict__ out) {
  int g = blockIdx.x, lane = threadIdx.x;
  int beg = starts[g], end = starts[g + 1];
  const unsigned int* hu = (const unsigned int*)h;
  float sx = 0.f, sy = 0.f;
  for (int n = beg; n < end; ++n) {
    unsigned int v = hu[(size_t)n * 64 + lane];
    sx += bflo(v);
    sy += bfhi(v);
  }
  float val = sx * Wf[2 * lane] + sy * Wf[2 * lane + 1];
#pragma unroll
  for (int off = 32; off > 0; off >>= 1) val += __shfl_down(val, off);
  if (lane == 0) out[g] = val + bf_[0];
}

extern "C" void kernel_launch(void* const* d_in, const int* in_sizes, int n_in,
                              void* d_out, int out_size, void* d_ws, size_t ws_size,
                              hipStream_t stream) {
  const float* x = (const float*)d_in[0];
  const int* ei = (const int*)d_in[1];
  const int* srcv = ei;
  const int* dstv = ei + N_EDGES;
  const int* batch = (const int*)d_in[3];
  const float* W0 = (const float*)d_in[4];
  const float* b0 = (const float*)d_in[5];
  const float* W1 = (const float*)d_in[6];
  const float* b1 = (const float*)d_in[7];
  const float* W2 = (const float*)d_in[8];
  const float* b2 = (const float*)d_in[9];
  const float* Wf = (const float*)d_in[10];
  const float* bf_ = (const float*)d_in[11];
  float* out = (float*)d_out;

  char* ws = (char*)d_ws;
  size_t o = 0;
  auto alloc = [&](size_t bytes) {
    size_t r = o;
    o = (o + bytes + 255) & ~(size_t)255;
    return r;
  };
  int* offs = (int*)(ws + alloc((N_NODES + 1) * sizeof(int)));
  int* cursor = (int*)(ws + alloc((size_t)N_NODES * sizeof(int)));
  int* csr = (int*)(ws + alloc((size_t)N_EDGES * sizeof(int)));
  int* aux = (int*)(ws + alloc(128 * sizeof(int)));
  int* starts = (int*)(ws + alloc((N_GRAPHS + 1) * sizeof(int)));
  unsigned short* h0 = (unsigned short*)(ws + alloc((size_t)N_NODES * H * 2));
  unsigned short* h = (unsigned short*)(ws + alloc((size_t)N_NODES * H * 2));
  unsigned short* zin = (unsigned short*)(ws + alloc((size_t)N_NODES * H * 2));

  hipMemsetAsync(cursor, 0, (size_t)N_NODES * sizeof(int), stream);
  k_hist<<<(N_EDGES + 255) / 256, 256, 0, stream>>>(dstv, cursor);
  k_scan1<<<98, 256, 0, stream>>>(cursor, offs, aux);
  k_scan2<<<1, 128, 0, stream>>>(aux, 98);
  k_scan3<<<98, 256, 0, stream>>>(offs, aux);
  hipMemcpyAsync(cursor, offs, (size_t)N_NODES * sizeof(int), hipMemcpyDeviceToDevice, stream);
  k_scatter<<<(N_EDGES + 255) / 256, 256, 0, stream>>>(srcv, dstv, cursor, csr);
  k_starts<<<(N_NODES + 255) / 256, 256, 0, stream>>>(batch, starts);

  const int nblk = (N_NODES + 63) / 64;
  k_lin<<<nblk, 256, 0, stream>>>(x, W0, b0, h0);
  for (int i = 0; i < DEPTH; ++i) {
    const unsigned short* hin = (i == 0) ? h0 : h;
    k_agg<<<N_NODES / 4, 256, 0, stream>>>(hin, offs, csr, zin);
    k_mlp<<<nblk, 256, 0, stream>>>(zin, W1 + (size_t)i * H * H, b1 + (size_t)i * H,
                                    W2 + (size_t)i * H * H, b2 + (size_t)i * H, h0, h);
  }
  k_pool<<<N_GRAPHS, 64, 0, stream>>>(h, starts, Wf, bf_, out);
}

// Round 3
// 678.336 us; speedup vs baseline: 2.2068x; 1.4856x over previous
//
#include <hip/hip_runtime.h>

#define N_NODES 100000
#define N_EDGES 1600000
#define N_GRAPHS 1000
#define H 128
#define DEPTH 4
#define NB 391        // buckets of 256 nodes
#define BCAP 4864     // bucket capacity (mean 4096, sd 64 -> +12 sigma)

typedef __attribute__((ext_vector_type(8))) short bf16x8;
typedef __attribute__((ext_vector_type(4))) float f32x4;

__device__ __forceinline__ unsigned short f2bf(float f) {
  unsigned int u = __float_as_uint(f);
  u += 0x7FFF + ((u >> 16) & 1);
  return (unsigned short)(u >> 16);
}
__device__ __forceinline__ float bflo(unsigned int v) { return __uint_as_float(v << 16); }
__device__ __forceinline__ float bfhi(unsigned int v) { return __uint_as_float(v & 0xFFFF0000u); }

// ---------------- CSR build: two-level counting sort ----------------
// Pass A: bucket counts (dst>>8) via LDS histogram
__global__ __launch_bounds__(256) void k_bcnt(const int* __restrict__ dst, int* __restrict__ gcnt) {
  __shared__ int c[NB];
  int tid = threadIdx.x, e0 = blockIdx.x * 4096;
  for (int i = tid; i < NB; i += 256) c[i] = 0;
  __syncthreads();
#pragma unroll
  for (int i = 0; i < 16; ++i) {
    int e = e0 + i * 256 + tid;
    if (e < N_EDGES) atomicAdd(&c[dst[e] >> 8], 1);
  }
  __syncthreads();
  for (int i = tid; i < NB; i += 256)
    if (c[i]) atomicAdd(&gcnt[i], c[i]);
}

// Pass scan: exclusive scan of 391 bucket counts
__global__ __launch_bounds__(512) void k_bscan(const int* __restrict__ gcnt, int* __restrict__ boff,
                                               int* __restrict__ cursor) {
  __shared__ int sh[512];
  int t = threadIdx.x;
  int v = (t < NB) ? gcnt[t] : 0;
  sh[t] = v;
  __syncthreads();
  for (int s = 1; s < 512; s <<= 1) {
    int x = (t >= s) ? sh[t - s] : 0;
    __syncthreads();
    sh[t] += x;
    __syncthreads();
  }
  if (t < NB) {
    int e = sh[t] - v;
    boff[t] = e;
    cursor[t] = e;
  }
  if (t == 0) boff[NB] = N_EDGES;
}

// Pass B: scatter packed (dstLocal<<17 | src) into bucket regions
__global__ __launch_bounds__(256) void k_bucket(const int* __restrict__ src, const int* __restrict__ dst,
                                                int* __restrict__ cursor, unsigned int* __restrict__ ebuf) {
  __shared__ int cnt[NB];
  __shared__ int base[NB];
  int tid = threadIdx.x;
  int e0 = blockIdx.x * 4096;
  for (int i = tid; i < NB; i += 256) cnt[i] = 0;
  __syncthreads();
  unsigned int pk[16];
  int bk[16], rk[16];
#pragma unroll
  for (int i = 0; i < 16; ++i) {
    int e = e0 + i * 256 + tid;
    if (e < N_EDGES) {
      int s = src[e], d = dst[e];
      bk[i] = d >> 8;
      pk[i] = ((unsigned int)(d & 255) << 17) | (unsigned int)s;
      rk[i] = atomicAdd(&cnt[bk[i]], 1);
    } else
      bk[i] = -1;
  }
  __syncthreads();
  for (int i = tid; i < NB; i += 256)
    base[i] = cnt[i] ? atomicAdd(&cursor[i], cnt[i]) : 0;
  __syncthreads();
#pragma unroll
  for (int i = 0; i < 16; ++i)
    if (bk[i] >= 0) ebuf[base[bk[i]] + rk[i]] = pk[i];
}

// Pass C: per-bucket LDS counting sort by dstLocal -> coalesced csr + per-node offs
__global__ __launch_bounds__(256) void k_bsort(const unsigned int* __restrict__ ebuf,
                                               const int* __restrict__ boff,
                                               int* __restrict__ csr, int* __restrict__ offs) {
  __shared__ unsigned int arr[BCAP];
  __shared__ unsigned int srt[BCAP];
  __shared__ unsigned short rnk[BCAP];
  __shared__ int cnt[256];
  __shared__ int off[257];
  int b = blockIdx.x, tid = threadIdx.x;
  int beg = boff[b], end = boff[b + 1];
  int ce = min(end - beg, BCAP);
  cnt[tid] = 0;
  __syncthreads();
  for (int i = tid; i < ce; i += 256) {
    unsigned int p = ebuf[beg + i];
    arr[i] = p;
    rnk[i] = (unsigned short)atomicAdd(&cnt[p >> 17], 1);
  }
  __syncthreads();
  int v = cnt[tid];
  off[tid + 1] = v;
  if (tid == 0) off[0] = 0;
  __syncthreads();
  for (int s = 1; s < 256; s <<= 1) {
    int x = (tid + 1 > s) ? off[tid + 1 - s] : 0;
    __syncthreads();
    off[tid + 1] += x;
    __syncthreads();
  }
  for (int i = tid; i < ce; i += 256) {
    unsigned int p = arr[i];
    srt[off[p >> 17] + rnk[i]] = p & 0x1FFFF;
  }
  __syncthreads();
  for (int i = tid; i < ce; i += 256) csr[beg + i] = (int)srt[i];
  int node = (b << 8) + tid;
  if (node < N_NODES) offs[node] = beg + off[tid];
  if (b == NB - 1 && tid == 0) offs[N_NODES] = N_EDGES;
}

// ---------------- stage W (fp32 KxN) transposed into LDS Wt[n][k] bf16, pad 136 ----------------
__device__ __forceinline__ void stage_w(const float* __restrict__ Wg, unsigned short* Wt, int tid) {
  for (int idx = tid; idx < 2048; idx += 256) {
    int ng4 = idx & 31, kp = idx >> 5;
    float4 r0 = *(const float4*)&Wg[(2 * kp) * H + 4 * ng4];
    float4 r1 = *(const float4*)&Wg[(2 * kp + 1) * H + 4 * ng4];
    unsigned int p0 = (unsigned int)f2bf(r0.x) | ((unsigned int)f2bf(r1.x) << 16);
    unsigned int p1 = (unsigned int)f2bf(r0.y) | ((unsigned int)f2bf(r1.y) << 16);
    unsigned int p2 = (unsigned int)f2bf(r0.z) | ((unsigned int)f2bf(r1.z) << 16);
    unsigned int p3 = (unsigned int)f2bf(r0.w) | ((unsigned int)f2bf(r1.w) << 16);
    *(unsigned int*)&Wt[(4 * ng4 + 0) * 136 + 2 * kp] = p0;
    *(unsigned int*)&Wt[(4 * ng4 + 1) * 136 + 2 * kp] = p1;
    *(unsigned int*)&Wt[(4 * ng4 + 2) * 136 + 2 * kp] = p2;
    *(unsigned int*)&Wt[(4 * ng4 + 3) * 136 + 2 * kp] = p3;
  }
}

// ---------------- Linear 0 (MFMA): h0 = relu(x @ W0 + b0), x fp32, h0 bf16 ----------------
__global__ __launch_bounds__(256) void k_lin(const float* __restrict__ in, const float* __restrict__ Wg,
                                             const float* __restrict__ bg, unsigned short* __restrict__ outp) {
  __shared__ unsigned short Wt[128 * 136];
  __shared__ unsigned short zs[64 * 136];
  int tid = threadIdx.x;
  int lane = tid & 63, w = tid >> 6;
  int q = lane >> 4, l16 = lane & 15;
  int n0 = blockIdx.x * 64;

  stage_w(Wg, Wt, tid);

  int row = n0 + w * 16 + l16;
  int rr = (row < N_NODES) ? row : 0;
  bf16x8 afrag[4];
#pragma unroll
  for (int ks = 0; ks < 4; ++ks) {
    const float* p = &in[(size_t)rr * H + ks * 32 + q * 8];
    float4 f0 = *(const float4*)p;
    float4 f1 = *(const float4*)(p + 4);
    bf16x8 a;
    a[0] = (short)f2bf(f0.x); a[1] = (short)f2bf(f0.y); a[2] = (short)f2bf(f0.z); a[3] = (short)f2bf(f0.w);
    a[4] = (short)f2bf(f1.x); a[5] = (short)f2bf(f1.y); a[6] = (short)f2bf(f1.z); a[7] = (short)f2bf(f1.w);
    afrag[ks] = a;
  }
  f32x4 acc[8];
#pragma unroll
  for (int ct = 0; ct < 8; ++ct) acc[ct] = (f32x4){0.f, 0.f, 0.f, 0.f};
  __syncthreads();
#pragma unroll
  for (int ct = 0; ct < 8; ++ct)
#pragma unroll
    for (int ks = 0; ks < 4; ++ks) {
      bf16x8 b = *(bf16x8*)&Wt[(ct * 16 + l16) * 136 + ks * 32 + q * 8];
      acc[ct] = __builtin_amdgcn_mfma_f32_16x16x32_bf16(afrag[ks], b, acc[ct], 0, 0, 0);
    }
#pragma unroll
  for (int ct = 0; ct < 8; ++ct) {
    float bb = bg[ct * 16 + l16];
#pragma unroll
    for (int r = 0; r < 4; ++r) {
      float v = fmaxf(acc[ct][r] + bb, 0.f);
      zs[(w * 16 + q * 4 + r) * 136 + ct * 16 + l16] = f2bf(v);
    }
  }
  __syncthreads();
  int node = tid >> 2, cb = (tid & 3) * 32;
  if (n0 + node < N_NODES) {
#pragma unroll
    for (int i = 0; i < 4; ++i) {
      uint4 v = *(uint4*)&zs[node * 136 + cb + i * 8];
      *(uint4*)&outp[(size_t)(n0 + node) * H + cb + i * 8] = v;
    }
  }
}

// ---------------- Aggregation: zin[n] = h[n] + sum_{CSR(n)} h[src], bf16 in/out, fp32 accum ----------------
__global__ __launch_bounds__(256) void k_agg(const unsigned short* __restrict__ hin, const int* __restrict__ offs,
                                             const int* __restrict__ csr, unsigned short* __restrict__ zin) {
  int node = blockIdx.x * 4 + (threadIdx.x >> 6);
  int lane = threadIdx.x & 63;
  if (node >= N_NODES) return;
  const unsigned int* hu = (const unsigned int*)hin;
  unsigned int self = hu[(size_t)node * 64 + lane];
  float sx = bflo(self), sy = bfhi(self);
  int beg = offs[node], end = offs[node + 1];
  for (int e = beg; e < end; e += 64) {
    int cnt = min(64, end - e);
    int idx = (lane < cnt) ? csr[e + lane] : 0;
    int j = 0;
    for (; j + 4 <= cnt; j += 4) {
      int s0 = __shfl(idx, j), s1 = __shfl(idx, j + 1), s2 = __shfl(idx, j + 2), s3 = __shfl(idx, j + 3);
      unsigned int v0 = hu[(size_t)s0 * 64 + lane];
      unsigned int v1 = hu[(size_t)s1 * 64 + lane];
      unsigned int v2 = hu[(size_t)s2 * 64 + lane];
      unsigned int v3 = hu[(size_t)s3 * 64 + lane];
      sx += bflo(v0); sy += bfhi(v0);
      sx += bflo(v1); sy += bfhi(v1);
      sx += bflo(v2); sy += bfhi(v2);
      sx += bflo(v3); sy += bfhi(v3);
    }
    for (; j < cnt; ++j) {
      int s = __shfl(idx, j);
      unsigned int v = hu[(size_t)s * 64 + lane];
      sx += bflo(v); sy += bfhi(v);
    }
  }
  unsigned int o = (unsigned int)f2bf(sx) | ((unsigned int)f2bf(sy) << 16);
  ((unsigned int*)zin)[(size_t)node * 64 + lane] = o;
}

// ---------------- Fused MLP (MFMA): h = relu( relu(zin@W1+b1)@W2 + b2 + h0 ) ----------------
__global__ __launch_bounds__(256) void k_mlp(const unsigned short* __restrict__ zin,
                                             const float* __restrict__ W1g, const float* __restrict__ b1g,
                                             const float* __restrict__ W2g, const float* __restrict__ b2g,
                                             const unsigned short* __restrict__ h0, unsigned short* __restrict__ h) {
  __shared__ unsigned short Wt[128 * 136];
  __shared__ unsigned short zs[64 * 136];
  int tid = threadIdx.x;
  int lane = tid & 63, w = tid >> 6;
  int q = lane >> 4, l16 = lane & 15;
  int n0 = blockIdx.x * 64;

  stage_w(W1g, Wt, tid);

  int row = n0 + w * 16 + l16;
  int rr = (row < N_NODES) ? row : 0;
  bf16x8 afrag[4];
#pragma unroll
  for (int ks = 0; ks < 4; ++ks)
    afrag[ks] = *(bf16x8*)&zin[(size_t)rr * H + ks * 32 + q * 8];

  f32x4 acc[8];
#pragma unroll
  for (int ct = 0; ct < 8; ++ct) acc[ct] = (f32x4){0.f, 0.f, 0.f, 0.f};
  __syncthreads();
#pragma unroll
  for (int ct = 0; ct < 8; ++ct)
#pragma unroll
    for (int ks = 0; ks < 4; ++ks) {
      bf16x8 b = *(bf16x8*)&Wt[(ct * 16 + l16) * 136 + ks * 32 + q * 8];
      acc[ct] = __builtin_amdgcn_mfma_f32_16x16x32_bf16(afrag[ks], b, acc[ct], 0, 0, 0);
    }
  __syncthreads();
  stage_w(W2g, Wt, tid);
#pragma unroll
  for (int ct = 0; ct < 8; ++ct) {
    float bb = b1g[ct * 16 + l16];
#pragma unroll
    for (int r = 0; r < 4; ++r) {
      float v = fmaxf(acc[ct][r] + bb, 0.f);
      zs[(w * 16 + q * 4 + r) * 136 + ct * 16 + l16] = f2bf(v);
    }
  }
  __syncthreads();
  bf16x8 a2[4];
#pragma unroll
  for (int ks = 0; ks < 4; ++ks)
    a2[ks] = *(bf16x8*)&zs[(w * 16 + l16) * 136 + ks * 32 + q * 8];
  f32x4 acc2[8];
#pragma unroll
  for (int ct = 0; ct < 8; ++ct) acc2[ct] = (f32x4){0.f, 0.f, 0.f, 0.f};
#pragma unroll
  for (int ct = 0; ct < 8; ++ct)
#pragma unroll
    for (int ks = 0; ks < 4; ++ks) {
      bf16x8 b = *(bf16x8*)&Wt[(ct * 16 + l16) * 136 + ks * 32 + q * 8];
      acc2[ct] = __builtin_amdgcn_mfma_f32_16x16x32_bf16(a2[ks], b, acc2[ct], 0, 0, 0);
    }
#pragma unroll
  for (int ct = 0; ct < 8; ++ct) {
    float bb = b2g[ct * 16 + l16];
#pragma unroll
    for (int r = 0; r < 4; ++r) {
      float v = acc2[ct][r] + bb;
      zs[(w * 16 + q * 4 + r) * 136 + ct * 16 + l16] = f2bf(v);
    }
  }
  __syncthreads();
  int node = tid >> 2, cb = (tid & 3) * 32;
  if (n0 + node < N_NODES) {
    size_t base = (size_t)(n0 + node) * H + cb;
#pragma unroll
    for (int i = 0; i < 4; ++i) {
      uint4 zv = *(uint4*)&zs[node * 136 + cb + i * 8];
      uint4 hv = *(const uint4*)&h0[base + i * 8];
      unsigned int zr[4] = {zv.x, zv.y, zv.z, zv.w};
      unsigned int hr[4] = {hv.x, hv.y, hv.z, hv.w};
      uint4 o;
      unsigned int orr[4];
#pragma unroll
      for (int j = 0; j < 4; ++j) {
        float a = fmaxf(bflo(zr[j]) + bflo(hr[j]), 0.f);
        float b = fmaxf(bfhi(zr[j]) + bfhi(hr[j]), 0.f);
        orr[j] = (unsigned int)f2bf(a) | ((unsigned int)f2bf(b) << 16);
      }
      o.x = orr[0]; o.y = orr[1]; o.z = orr[2]; o.w = orr[3];
      *(uint4*)&h[base + i * 8] = o;
    }
  }
}

// ---------------- Pooling ----------------
__global__ void k_starts(const int* __restrict__ batch, int* __restrict__ starts) {
  int n = blockIdx.x * 256 + threadIdx.x;
  if (n >= N_NODES) return;
  int b = batch[n];
  if (n == 0) {
    for (int g = 0; g <= b; ++g) starts[g] = 0;
  } else {
    int bp = batch[n - 1];
    for (int g = bp + 1; g <= b; ++g) starts[g] = n;
  }
  if (n == N_NODES - 1) {
    for (int g = b + 1; g <= N_GRAPHS; ++g) starts[g] = N_NODES;
  }
}

__global__ __launch_bounds__(256) void k_pool(const unsigned short* __restrict__ h, const int* __restrict__ starts,
                                              const float* __restrict__ Wf, const float* __restrict__ bf_,
                                              float* __restrict__ out) {
  __shared__ float r[4];
  int g = blockIdx.x, tid = threadIdx.x;
  int lane = tid & 63, w = tid >> 6;
  int beg = starts[g], end = starts[g + 1];
  const unsigned int* hu = (const unsigned int*)h;
  float sx = 0.f, sy = 0.f;
  for (int n = beg + w; n < end; n += 4) {
    unsigned int v = hu[(size_t)n * 64 + lane];
    sx += bflo(v);
    sy += bfhi(v);
  }
  float val = sx * Wf[2 * lane] + sy * Wf[2 * lane + 1];
#pragma unroll
  for (int off = 32; off > 0; off >>= 1) val += __shfl_down(val, off);
  if (lane == 0) r[w] = val;
  __syncthreads();
  if (tid == 0) out[g] = r[0] + r[1] + r[2] + r[3] + bf_[0];
}

extern "C" void kernel_launch(void* const* d_in, const int* in_sizes, int n_in,
                              void* d_out, int out_size, void* d_ws, size_t ws_size,
                              hipStream_t stream) {
  const float* x = (const float*)d_in[0];
  const int* ei = (const int*)d_in[1];
  const int* srcv = ei;
  const int* dstv = ei + N_EDGES;
  const int* batch = (const int*)d_in[3];
  const float* W0 = (const float*)d_in[4];
  const float* b0 = (const float*)d_in[5];
  const float* W1 = (const float*)d_in[6];
  const float* b1 = (const float*)d_in[7];
  const float* W2 = (const float*)d_in[8];
  const float* b2 = (const float*)d_in[9];
  const float* Wf = (const float*)d_in[10];
  const float* bf_ = (const float*)d_in[11];
  float* out = (float*)d_out;

  char* ws = (char*)d_ws;
  size_t o = 0;
  auto alloc = [&](size_t bytes) {
    size_t r = o;
    o = (o + bytes + 255) & ~(size_t)255;
    return r;
  };
  int* offs = (int*)(ws + alloc((N_NODES + 1) * sizeof(int)));
  int* gcnt = (int*)(ws + alloc(NB * sizeof(int)));
  int* boff = (int*)(ws + alloc((NB + 1) * sizeof(int)));
  int* cursor = (int*)(ws + alloc(NB * sizeof(int)));
  unsigned int* ebuf = (unsigned int*)(ws + alloc((size_t)N_EDGES * 4));
  int* csr = (int*)(ws + alloc((size_t)N_EDGES * sizeof(int)));
  int* starts = (int*)(ws + alloc((N_GRAPHS + 1) * sizeof(int)));
  unsigned short* h0 = (unsigned short*)(ws + alloc((size_t)N_NODES * H * 2));
  unsigned short* h = (unsigned short*)(ws + alloc((size_t)N_NODES * H * 2));
  unsigned short* zin = (unsigned short*)(ws + alloc((size_t)N_NODES * H * 2));

  hipMemsetAsync(gcnt, 0, NB * sizeof(int), stream);
  k_bcnt<<<NB, 256, 0, stream>>>(dstv, gcnt);
  k_bscan<<<1, 512, 0, stream>>>(gcnt, boff, cursor);
  k_bucket<<<NB, 256, 0, stream>>>(srcv, dstv, cursor, ebuf);
  k_bsort<<<NB, 256, 0, stream>>>(ebuf, boff, csr, offs);
  k_starts<<<(N_NODES + 255) / 256, 256, 0, stream>>>(batch, starts);

  const int nblk = (N_NODES + 63) / 64;
  k_lin<<<nblk, 256, 0, stream>>>(x, W0, b0, h0);
  for (int i = 0; i < DEPTH; ++i) {
    const unsigned short* hin = (i == 0) ? h0 : h;
    k_agg<<<N_NODES / 4, 256, 0, stream>>>(hin, offs, csr, zin);
    k_mlp<<<nblk, 256, 0, stream>>>(zin, W1 + (size_t)i * H * H, b1 + (size_t)i * H,
                                    W2 + (size_t)i * H * H, b2 + (size_t)i * H, h0, h);
  }
  k_pool<<<N_GRAPHS, 256, 0, stream>>>(h, starts, Wf, bf_, out);
}